// Round 1
// baseline (132.325 us; speedup 1.0000x reference)
//
#include <hip/hip_runtime.h>

typedef __bf16 bf16;
typedef __bf16 bf16x8 __attribute__((ext_vector_type(8)));
typedef float f32x4 __attribute__((ext_vector_type(4)));
typedef unsigned short u16;
typedef u16 u16x8 __attribute__((ext_vector_type(8)));
typedef unsigned int u32;

#define BATCH 64
#define NODES 512
#define AMINO 64
#define NTYPES 20
#define RMAX 13
#define WCOLS (RMAX * 32)   // 416 fp32 per amino row of W
#define PADA 72             // padded amino stride in LDS planes (elements)

__constant__ int c_res_lens[NTYPES] = {4,10,7,7,5,8,8,3,9,7,7,8,7,10,6,5,6,13,11,6};

// fp32 -> bf16, exact round-to-nearest-even, pure bit ops (proven in prior rounds)
__device__ __forceinline__ u16 f2bf(float f) {
    u32 u; __builtin_memcpy(&u, &f, 4);
    u32 r = u + 0x7FFFu + ((u >> 16) & 1u);
    return (u16)(r >> 16);
}

// int64 vs int32 probe for type_ids: odd words all-zero <=> int64 high halves.
__device__ __forceinline__ int detect_i64(const int* __restrict__ p) {
    int z = 0;
#pragma unroll
    for (int k = 0; k < 16; ++k) z |= p[2 * k + 1];
    return z == 0;
}
__device__ __forceinline__ int tid_at(const int* __restrict__ p, int n, int is64) {
    return p[is64 ? 2 * n : n];
}

// ---------------- single fused kernel ----------------
// block = (node n, m-tile m): 16 batches. 4 waves; wave w handles r = w, w+4, ...
// - s0 (exclusive prefix of residue lengths) computed per-wave from type_ids.
// - B fragments built in-loop directly from fp32 W (L2-resident, 2.13 MB),
//   identical index math to the old prep swizzle:
//   lane l holds W[t][a = kh*32 + (l>>4)*8 + i][j = (2r+jj)*16 + (l&15)], i=0..7
__global__ __launch_bounds__(256) void fused_kernel(const float* __restrict__ x,
                                                    const float* __restrict__ W,
                                                    const int* __restrict__ type_ids,
                                                    float* __restrict__ out,
                                                    int G) {
    __shared__ __align__(16) u16 planes[3][16][PADA];   // [v][b16][a pad72] = 6912 B

    const int bid = blockIdx.x;
    const int n = bid >> 2;
    const int m = bid & 3;
    const int tid = threadIdx.x;
    const int w = tid >> 6;
    const int l = tid & 63;

    const int is64 = detect_i64(type_ids);
    const int t = tid_at(type_ids, n, is64);
    const int len = c_res_lens[t];

    // ---- stage x[m*16..m*16+15, n, :, :] into bf16 v-planes ----
    // wave w, iter i -> batch row b16 = i*4 + w; lane l -> amino a = l.
#pragma unroll
    for (int i = 0; i < 4; ++i) {
        int b16 = i * 4 + w;
        const float* src = x + ((size_t)(m * 16 + b16) * NODES + n) * 192 + l * 3;
        float v0 = src[0];
        float v1 = src[1];
        float v2 = src[2];
        planes[0][b16][l] = f2bf(v0);
        planes[1][b16][l] = f2bf(v1);
        planes[2][b16][l] = f2bf(v2);
    }

    // ---- s0 = sum of res_lens[type_ids[k]] for k < n (per-wave, overlaps staging) ----
    int part = 0;
    for (int k = l; k < n; k += 64) part += c_res_lens[tid_at(type_ids, k, is64)];
#pragma unroll
    for (int off = 1; off < 64; off <<= 1) part += __shfl_xor(part, off);
    const int s0 = part;

    __syncthreads();

    const int q = l >> 4;
    const int c = l & 15;

    // ---- preload A fragments: lane holds A[row=c][k=kh*32+q*8+i] ----
    union Frag { u16x8 u; bf16x8 b; };
    Frag Af[3][2];
#pragma unroll
    for (int v = 0; v < 3; ++v)
#pragma unroll
        for (int kh = 0; kh < 2; ++kh)
            Af[v][kh].u = *(const u16x8*)(&planes[v][c][kh * 32 + q * 8]);

    // per-lane W base: row block q*8 of type t, column c
    const float* Wqc = W + (size_t)(t * AMINO + q * 8) * WCOLS + c;

    for (int r = w; r < len; r += 4) {
        // ---- build B fragments directly from fp32 W (strided L2 loads + cvt) ----
        Frag Bf[2][2];
#pragma unroll
        for (int jj = 0; jj < 2; ++jj)
#pragma unroll
            for (int kh = 0; kh < 2; ++kh) {
                const float* p = Wqc + kh * 32 * WCOLS + r * 32 + jj * 16;
                u16x8 v;
#pragma unroll
                for (int i = 0; i < 8; ++i) v[i] = f2bf(p[i * WCOLS]);
                Bf[jj][kh].u = v;
            }

        const int g = s0 + r;   // output row index within G

        f32x4 acc[2][3];
        const f32x4 z = {0.f, 0.f, 0.f, 0.f};
#pragma unroll
        for (int jj = 0; jj < 2; ++jj)
#pragma unroll
            for (int v = 0; v < 3; ++v) {
                f32x4 a0 = __builtin_amdgcn_mfma_f32_16x16x32_bf16(Af[v][0].b, Bf[jj][0].b, z, 0, 0, 0);
                acc[jj][v] = __builtin_amdgcn_mfma_f32_16x16x32_bf16(Af[v][1].b, Bf[jj][1].b, a0, 0, 0, 0);
            }

        // direct store: lane writes 3 consecutive fp32 (v=0..2) per (row, atom);
        // 16 lanes (c) cover 192 B contiguous per (q, reg, jj) segment.
#pragma unroll
        for (int reg = 0; reg < 4; ++reg) {
            float* rowp = out + ((size_t)(m * 16 + q * 4 + reg) * G + g) * 96;
#pragma unroll
            for (int jj = 0; jj < 2; ++jj) {
                float* p2 = rowp + (jj * 16 + c) * 3;
                p2[0] = acc[jj][0][reg];
                p2[1] = acc[jj][1][reg];
                p2[2] = acc[jj][2][reg];
            }
        }
    }
}

extern "C" void kernel_launch(void* const* d_in, const int* in_sizes, int n_in,
                              void* d_out, int out_size, void* d_ws, size_t ws_size,
                              hipStream_t stream) {
    const float* x = (const float*)d_in[0];    // fp32 (B, N, 64, 3)
    const float* W = (const float*)d_in[1];    // fp32 (20, 64, 416)
    const int* type_ids = (const int*)d_in[2]; // int32 or int64 (autodetected), 512
    int G = out_size / (BATCH * 32 * 3);       // valid (node,residue) rows

    fused_kernel<<<NODES * 4, 256, 0, stream>>>(x, W, type_ids, (float*)d_out, G);
}